// Round 12
// baseline (259.955 us; speedup 1.0000x reference)
//
#include <hip/hip_runtime.h>
#include <stdint.h>

#define NN 50000
#define EE 800000
#define CAP 48        // slots/node; deg ~Poisson(16), P(overflow) negligible
#define NXCD 8
#define NPX 6250      // NN / NXCD
#define EPB 2048      // edges per scatter block
#define NCHUNK 391    // ceil(EE / EPB)

typedef __bf16 bf16x8 __attribute__((ext_vector_type(8)));
typedef float  f32x4  __attribute__((ext_vector_type(4)));

__device__ __forceinline__ float bflo(unsigned int w){ union{unsigned int i;float f;}c; c.i=w<<16; return c.f; }
__device__ __forceinline__ float bfhi(unsigned int w){ union{unsigned int i;float f;}c; c.i=w&0xFFFF0000u; return c.f; }
__device__ __forceinline__ float bfs(unsigned short u){ union{unsigned int i;float f;}c; c.i=((unsigned int)u)<<16; return c.f; }
__device__ __forceinline__ bf16x8 bf8_zero(){
  bf16x8 v;
  #pragma unroll
  for (int j=0;j<8;++j) v[j]=(__bf16)0.f;
  return v;
}

// ---------- prep: W0 [256,128] f32 -> bf16 MFMA-B fragment table Wg[32][128][8] ----------
__global__ __launch_bounds__(256) void k_prepW0(const float* __restrict__ W0,
                                                __bf16* __restrict__ Wg){
  int tg = blockIdx.x*256 + threadIdx.x;
  if (tg >= 4096) return;
  int k8 = tg >> 7, n = tg & 127;
  bf16x8 v;
  #pragma unroll
  for (int j=0;j<8;++j) v[j] = (__bf16)W0[(k8*8+j)*128 + n];
  *(bf16x8*)(Wg + ((size_t)(k8*128 + n))*8) = v;
}

// ---------- GEMM0 (MFMA bf16, LDS-free): z0b = x @ W0, + el0/er0 + self-loop CSR init ----------
__global__ __launch_bounds__(256) void k_gemm0(const float* __restrict__ x,
    const __bf16* __restrict__ Wg, const float* __restrict__ al0, const float* __restrict__ ar0,
    __bf16* __restrict__ z0b, float* __restrict__ el0, float* __restrict__ er0,
    int* __restrict__ cursor, int* __restrict__ csrv){
  const int tid = threadIdx.x;
  const int wv = tid >> 6, ln = tid & 63, q = ln >> 4, mr = ln & 15;
  const int nhalf = wv & 1, mhalf = wv >> 1;
  const int m0w = blockIdx.x*64 + mhalf*32;
  const int n0w = nhalf*64;
  f32x4 acc[2][4];
  #pragma unroll
  for (int mt=0;mt<2;++mt)
    #pragma unroll
    for (int nt=0;nt<4;++nt) acc[mt][nt] = (f32x4){0.f,0.f,0.f,0.f};
  const bool av0 = (m0w + mr) < NN;
  const bool av1 = (m0w + 16 + mr) < NN;
  const float* xr0 = x + (size_t)(m0w + mr)*256;
  const float* xr1 = x + (size_t)(m0w + 16 + mr)*256;
  #pragma unroll
  for (int kc=0;kc<8;++kc){
    int ko = kc*32 + q*8;
    bf16x8 a0 = bf8_zero(), a1 = bf8_zero();
    if (av0){
      float4 p = *(const float4*)(xr0 + ko);
      float4 p2 = *(const float4*)(xr0 + ko + 4);
      a0[0]=(__bf16)p.x; a0[1]=(__bf16)p.y; a0[2]=(__bf16)p.z; a0[3]=(__bf16)p.w;
      a0[4]=(__bf16)p2.x; a0[5]=(__bf16)p2.y; a0[6]=(__bf16)p2.z; a0[7]=(__bf16)p2.w;
    }
    if (av1){
      float4 p = *(const float4*)(xr1 + ko);
      float4 p2 = *(const float4*)(xr1 + ko + 4);
      a1[0]=(__bf16)p.x; a1[1]=(__bf16)p.y; a1[2]=(__bf16)p.z; a1[3]=(__bf16)p.w;
      a1[4]=(__bf16)p2.x; a1[5]=(__bf16)p2.y; a1[6]=(__bf16)p2.z; a1[7]=(__bf16)p2.w;
    }
    const __bf16* wb = Wg + ((size_t)((kc*4+q)*128 + n0w + mr))*8;
    #pragma unroll
    for (int nt=0;nt<4;++nt){
      bf16x8 bf = *(const bf16x8*)(wb + (size_t)nt*16*8);
      acc[0][nt] = __builtin_amdgcn_mfma_f32_16x16x32_bf16(a0, bf, acc[0][nt], 0,0,0);
      acc[1][nt] = __builtin_amdgcn_mfma_f32_16x16x32_bf16(a1, bf, acc[1][nt], 0,0,0);
    }
  }
  float alv[4], arv[4];
  #pragma unroll
  for (int nt=0;nt<4;++nt){ int c = n0w + nt*16 + mr; alv[nt]=al0[c]; arv[nt]=ar0[c]; }
  #pragma unroll
  for (int mt=0;mt<2;++mt){
    #pragma unroll
    for (int r=0;r<4;++r){
      int grow = m0w + mt*16 + q*4 + r;
      if (grow < NN){
        #pragma unroll
        for (int nt=0;nt<4;++nt)
          z0b[(size_t)grow*128 + n0w + nt*16 + mr] = (__bf16)acc[mt][nt][r];
      }
      float pl0 = acc[mt][0][r]*alv[0] + acc[mt][1][r]*alv[1];
      float pr0 = acc[mt][0][r]*arv[0] + acc[mt][1][r]*arv[1];
      float pl1 = acc[mt][2][r]*alv[2] + acc[mt][3][r]*alv[3];
      float pr1 = acc[mt][2][r]*arv[2] + acc[mt][3][r]*arv[3];
      #pragma unroll
      for (int off=1; off<16; off<<=1){
        pl0 += __shfl_xor(pl0, off, 16); pr0 += __shfl_xor(pr0, off, 16);
        pl1 += __shfl_xor(pl1, off, 16); pr1 += __shfl_xor(pr1, off, 16);
      }
      if (mr==0 && grow<NN){
        el0[grow*4 + 2*nhalf]   = pl0; er0[grow*4 + 2*nhalf]   = pr0;
        el0[grow*4 + 2*nhalf+1] = pl1; er0[grow*4 + 2*nhalf+1] = pr1;
        if (nhalf==0){ csrv[(size_t)grow*CAP] = grow; cursor[grow] = 1; }
      }
    }
  }
}

// ---------- scatter (XCD-partitioned, single pass; round-10 measured form) ----------
__global__ __launch_bounds__(256) void k_scatter(const int* __restrict__ src,
    const int* __restrict__ dst, int* __restrict__ cursor, int* __restrict__ csrv){
  const int xcd = blockIdx.x & 7;
  const int chunk = blockIdx.x >> 3;
  const int lo = xcd*NPX, hi = lo + NPX;
  int e = chunk*EPB + threadIdx.x;
  #pragma unroll
  for (int it=0; it<EPB/256; ++it, e += 256){
    if (e < EE){
      int d = dst[e];
      if (d >= lo && d < hi){
        int s = src[e];
        unsigned int inv = (s==d) ? 0x80000000u : 0u;
        int pos = atomicAdd(&cursor[d], 1);
        csrv[(size_t)d*CAP + pos] = (int)((unsigned int)s | inv);
      }
    }
  }
}

// ---------- wedge0: one thread per CSR slot -> 4-head bf16 softmax weights ----------
__global__ __launch_bounds__(256) void k_wedge0(const int* __restrict__ csrv,
    const int* __restrict__ cursor, const float* __restrict__ el0,
    const float* __restrict__ er0, unsigned short* __restrict__ wt){
  int slot = blockIdx.x*256 + threadIdx.x;
  int node = slot / CAP;
  int si = slot - node*CAP;
  if (si >= cursor[node]) return;
  int v = csrv[slot];
  int u = v & 0x7FFFFFFF;
  float4 ls = *(const float4*)(el0 + (size_t)u*4);
  float4 rd = *(const float4*)(er0 + (size_t)node*4);
  float e0=ls.x+rd.x; e0 = e0>0.f?e0:0.2f*e0;
  float e1=ls.y+rd.y; e1 = e1>0.f?e1:0.2f*e1;
  float e2=ls.z+rd.z; e2 = e2>0.f?e2:0.2f*e2;
  float e3=ls.w+rd.w; e3 = e3>0.f?e3:0.2f*e3;
  bool inv = (v < 0);
  union { __bf16 b[4]; uint2 u2; } pk;
  pk.b[0]=(__bf16)(inv?0.f:__expf(e0)); pk.b[1]=(__bf16)(inv?0.f:__expf(e1));
  pk.b[2]=(__bf16)(inv?0.f:__expf(e2)); pk.b[3]=(__bf16)(inv?0.f:__expf(e3));
  *(uint2*)(wt + (size_t)slot*4) = pk.u2;
}

// ---------- agg0: wave/node, 2 feats/lane; explicit 16/8/4/1 batches ----------
__global__ __launch_bounds__(256) void k_agg0(const unsigned short* __restrict__ z0b,
    const unsigned short* __restrict__ wt,
    const int* __restrict__ cursor, const int* __restrict__ csrv,
    const float* __restrict__ b0, unsigned short* __restrict__ hb){
  int lane = threadIdx.x & 63;
  int i = __builtin_amdgcn_readfirstlane(blockIdx.x*4 + (threadIdx.x >> 6));
  int h1 = lane >> 4;
  int lane2 = lane << 1;
  float ax=0.f, ay=0.f, s=0.f;
  int p = i*CAP, pe = p + cursor[i];
  for (; p+16<=pe; p+=16){
    int4 a0 = *(const int4*)(csrv + p);
    int4 a1 = *(const int4*)(csrv + p + 4);
    int4 a2 = *(const int4*)(csrv + p + 8);
    int4 a3 = *(const int4*)(csrv + p + 12);
    int v[16] = {a0.x,a0.y,a0.z,a0.w,a1.x,a1.y,a1.z,a1.w,
                 a2.x,a2.y,a2.z,a2.w,a3.x,a3.y,a3.z,a3.w};
    float w[16];
    #pragma unroll
    for (int j=0;j<16;++j) w[j] = bfs(wt[(size_t)(p+j)*4 + h1]);
    unsigned int zw[16];
    #pragma unroll
    for (int j=0;j<16;++j)
      zw[j] = *(const unsigned int*)(z0b + (size_t)(v[j]&0x7FFFFFFF)*128 + lane2);
    #pragma unroll
    for (int j=0;j<16;++j){
      s += w[j]; ax = fmaf(w[j], bflo(zw[j]), ax); ay = fmaf(w[j], bfhi(zw[j]), ay);
    }
  }
  for (; p+8<=pe; p+=8){
    int4 a0 = *(const int4*)(csrv + p);
    int4 a1 = *(const int4*)(csrv + p + 4);
    int v[8] = {a0.x,a0.y,a0.z,a0.w,a1.x,a1.y,a1.z,a1.w};
    float w[8];
    #pragma unroll
    for (int j=0;j<8;++j) w[j] = bfs(wt[(size_t)(p+j)*4 + h1]);
    unsigned int zw[8];
    #pragma unroll
    for (int j=0;j<8;++j)
      zw[j] = *(const unsigned int*)(z0b + (size_t)(v[j]&0x7FFFFFFF)*128 + lane2);
    #pragma unroll
    for (int j=0;j<8;++j){
      s += w[j]; ax = fmaf(w[j], bflo(zw[j]), ax); ay = fmaf(w[j], bfhi(zw[j]), ay);
    }
  }
  for (; p+4<=pe; p+=4){
    int4 a0 = *(const int4*)(csrv + p);
    int v[4] = {a0.x,a0.y,a0.z,a0.w};
    float w[4];
    #pragma unroll
    for (int j=0;j<4;++j) w[j] = bfs(wt[(size_t)(p+j)*4 + h1]);
    unsigned int zw[4];
    #pragma unroll
    for (int j=0;j<4;++j)
      zw[j] = *(const unsigned int*)(z0b + (size_t)(v[j]&0x7FFFFFFF)*128 + lane2);
    #pragma unroll
    for (int j=0;j<4;++j){
      s += w[j]; ax = fmaf(w[j], bflo(zw[j]), ax); ay = fmaf(w[j], bfhi(zw[j]), ay);
    }
  }
  for (; p<pe; ++p){
    int u = csrv[p] & 0x7FFFFFFF;
    float w = bfs(wt[(size_t)p*4 + h1]);
    unsigned int zw = *(const unsigned int*)(z0b + (size_t)u*128 + lane2);
    s += w; ax = fmaf(w, bflo(zw), ax); ay = fmaf(w, bfhi(zw), ay);
  }
  float inv = 1.f/s;
  float ox = ax*inv + b0[lane*2], oy = ay*inv + b0[lane*2+1];
  ox = ox>0.f?ox:__expf(ox)-1.f; oy = oy>0.f?oy:__expf(oy)-1.f;
  union { __bf16 b[2]; unsigned int u; } pk;
  pk.b[0]=(__bf16)ox; pk.b[1]=(__bf16)oy;
  *(unsigned int*)(hb + (size_t)i*128 + lane2) = pk.u;
}

// ---------- GEMM1 (MFMA bf16): z1b = h @ W1 [128x40], + fused el1/er1 ----------
__global__ __launch_bounds__(256) void k_gemm1(const __bf16* __restrict__ hb,
    const float* __restrict__ W1, const float* __restrict__ al1, const float* __restrict__ ar1,
    __bf16* __restrict__ z1b, float* __restrict__ el1, float* __restrict__ er1){
  __shared__ __bf16 Blds[16][48][8];
  const int tid = threadIdx.x;
  for (int t=tid; t<16*48*8; t+=256) (&Blds[0][0][0])[t] = (__bf16)0.f;
  __syncthreads();
  for (int t=tid; t<5120; t+=256){
    int k = t/40, n = t - k*40;
    Blds[k>>3][n][k&7] = (__bf16)W1[t];
  }
  __syncthreads();
  const int wm = tid >> 6, ln = tid & 63, q = ln >> 4, mr = ln & 15;
  const int m0 = blockIdx.x*64 + wm*16;
  const int arow = m0 + mr;
  const bool av = (arow < NN);
  f32x4 acc[3];
  #pragma unroll
  for (int nt=0;nt<3;++nt) acc[nt] = (f32x4){0.f,0.f,0.f,0.f};
  #pragma unroll
  for (int kc=0;kc<4;++kc){
    bf16x8 af = bf8_zero();
    if (av) af = *(const bf16x8*)(hb + (size_t)arow*128 + kc*32 + q*8);
    #pragma unroll
    for (int nt=0;nt<3;++nt){
      bf16x8 bf = *(const bf16x8*)&Blds[kc*4+q][nt*16+mr][0];
      acc[nt] = __builtin_amdgcn_mfma_f32_16x16x32_bf16(af, bf, acc[nt], 0,0,0);
    }
  }
  float alv[3], arv[3];
  #pragma unroll
  for (int nt=0;nt<3;++nt){
    int c = nt*16+mr;
    alv[nt] = (c<40) ? al1[c] : 0.f;
    arv[nt] = (c<40) ? ar1[c] : 0.f;
  }
  #pragma unroll
  for (int r=0;r<4;++r){
    int grow = m0 + q*4 + r;
    if (grow < NN){
      #pragma unroll
      for (int nt=0;nt<3;++nt){
        int c = nt*16+mr;
        if (c < 40) z1b[(size_t)grow*40 + c] = (__bf16)acc[nt][r];
      }
    }
    float pl = acc[0][r]*alv[0] + acc[1][r]*alv[1] + acc[2][r]*alv[2];
    float pr = acc[0][r]*arv[0] + acc[1][r]*arv[1] + acc[2][r]*arv[2];
    #pragma unroll
    for (int off=1; off<16; off<<=1){ pl += __shfl_xor(pl, off, 16); pr += __shfl_xor(pr, off, 16); }
    if (mr==0 && grow<NN){ el1[grow]=pl; er1[grow]=pr; }
  }
}

// ---------- agg1: wave/node; in-loop exp (explicit 16/8/4/1 batches); out f32 ----------
__global__ __launch_bounds__(256) void k_agg1(const unsigned short* __restrict__ z1b,
    const float* __restrict__ el1, const float* __restrict__ er1,
    const int* __restrict__ cursor, const int* __restrict__ csrv,
    const float* __restrict__ b1, float* __restrict__ out){
  int lane = threadIdx.x & 63;
  int i = __builtin_amdgcn_readfirstlane(blockIdx.x*4 + (threadIdx.x >> 6));
  int fl = (lane < 20) ? (lane<<1) : 0;
  float eri = er1[i];
  float ax=0.f, ay=0.f, s=0.f;
  int p = i*CAP, pe = p + cursor[i];
  for (; p+16<=pe; p+=16){
    int4 a0 = *(const int4*)(csrv + p);
    int4 a1 = *(const int4*)(csrv + p + 4);
    int4 a2 = *(const int4*)(csrv + p + 8);
    int4 a3 = *(const int4*)(csrv + p + 12);
    int v[16] = {a0.x,a0.y,a0.z,a0.w,a1.x,a1.y,a1.z,a1.w,
                 a2.x,a2.y,a2.z,a2.w,a3.x,a3.y,a3.z,a3.w};
    float el[16];
    #pragma unroll
    for (int j=0;j<16;++j) el[j] = el1[v[j]&0x7FFFFFFF];
    unsigned int zw[16];
    #pragma unroll
    for (int j=0;j<16;++j)
      zw[j] = *(const unsigned int*)(z1b + (size_t)(v[j]&0x7FFFFFFF)*40 + fl);
    #pragma unroll
    for (int j=0;j<16;++j){
      float e = el[j] + eri; e = e>0.f ? e : 0.2f*e;
      float w = (v[j]>=0) ? __expf(e) : 0.f;
      s += w; ax = fmaf(w, bflo(zw[j]), ax); ay = fmaf(w, bfhi(zw[j]), ay);
    }
  }
  for (; p+8<=pe; p+=8){
    int4 a0 = *(const int4*)(csrv + p);
    int4 a1 = *(const int4*)(csrv + p + 4);
    int v[8] = {a0.x,a0.y,a0.z,a0.w,a1.x,a1.y,a1.z,a1.w};
    float el[8];
    #pragma unroll
    for (int j=0;j<8;++j) el[j] = el1[v[j]&0x7FFFFFFF];
    unsigned int zw[8];
    #pragma unroll
    for (int j=0;j<8;++j)
      zw[j] = *(const unsigned int*)(z1b + (size_t)(v[j]&0x7FFFFFFF)*40 + fl);
    #pragma unroll
    for (int j=0;j<8;++j){
      float e = el[j] + eri; e = e>0.f ? e : 0.2f*e;
      float w = (v[j]>=0) ? __expf(e) : 0.f;
      s += w; ax = fmaf(w, bflo(zw[j]), ax); ay = fmaf(w, bfhi(zw[j]), ay);
    }
  }
  for (; p+4<=pe; p+=4){
    int4 a0 = *(const int4*)(csrv + p);
    int v[4] = {a0.x,a0.y,a0.z,a0.w};
    float el[4];
    #pragma unroll
    for (int j=0;j<4;++j) el[j] = el1[v[j]&0x7FFFFFFF];
    unsigned int zw[4];
    #pragma unroll
    for (int j=0;j<4;++j)
      zw[j] = *(const unsigned int*)(z1b + (size_t)(v[j]&0x7FFFFFFF)*40 + fl);
    #pragma unroll
    for (int j=0;j<4;++j){
      float e = el[j] + eri; e = e>0.f ? e : 0.2f*e;
      float w = (v[j]>=0) ? __expf(e) : 0.f;
      s += w; ax = fmaf(w, bflo(zw[j]), ax); ay = fmaf(w, bfhi(zw[j]), ay);
    }
  }
  for (; p<pe; ++p){
    int v = csrv[p]; int u = v & 0x7FFFFFFF;
    float l = el1[u];
    unsigned int zw = *(const unsigned int*)(z1b + (size_t)u*40 + fl);
    float e = l + eri; e = e>0.f ? e : 0.2f*e;
    float w = (v>=0) ? __expf(e) : 0.f;
    s += w; ax = fmaf(w, bflo(zw), ax); ay = fmaf(w, bfhi(zw), ay);
  }
  if (lane < 20){
    float inv = 1.f/s;
    float ox = ax*inv + b1[lane*2], oy = ay*inv + b1[lane*2+1];
    ox = ox>0.f?ox:__expf(ox)-1.f; oy = oy>0.f?oy:__expf(oy)-1.f;
    *(float2*)(out + (size_t)i*40 + (lane<<1)) = make_float2(ox, oy);
  }
}

extern "C" void kernel_launch(void* const* d_in, const int* in_sizes, int n_in,
                              void* d_out, int out_size, void* d_ws, size_t ws_size,
                              hipStream_t stream){
  const float* x   = (const float*)d_in[0];
  const int*   src = (const int*)d_in[1];
  const int*   dst = (const int*)d_in[2];
  const float* W0  = (const float*)d_in[3];
  const float* al0 = (const float*)d_in[4];
  const float* ar0 = (const float*)d_in[5];
  const float* b0  = (const float*)d_in[6];
  const float* W1  = (const float*)d_in[7];
  const float* al1 = (const float*)d_in[8];
  const float* ar1 = (const float*)d_in[9];
  const float* b1  = (const float*)d_in[10];
  float* out = (float*)d_out;

  // ws layout (~61 MB)
  __bf16* z0b = (__bf16*)d_ws;                       // NN*128 bf16      12.8 MB
  __bf16* hb  = z0b + (size_t)NN*128;                // NN*128 bf16      12.8 MB
  __bf16* z1b = hb  + (size_t)NN*128;                // NN*40  bf16       4.0 MB
  __bf16* Wg  = z1b + (size_t)NN*40;                 // 32768 bf16       64 KB
  unsigned short* wt = (unsigned short*)(Wg + 32768);// NN*CAP*4 bf16    19.2 MB
  float* el0 = (float*)(wt + (size_t)NN*CAP*4);      // NN*4
  float* er0 = el0 + (size_t)NN*4;                   // NN*4
  float* el1 = er0 + (size_t)NN*4;                   // NN
  float* er1 = el1 + NN;                             // NN
  int* cursor = (int*)(er1 + NN);                    // NN
  int* csrv   = cursor + NN;                         // NN*CAP            9.6 MB

  k_prepW0 <<<16, 256, 0, stream>>>(W0, Wg);
  k_gemm0  <<<(NN+63)/64, 256, 0, stream>>>(x, Wg, al0, ar0, z0b, el0, er0, cursor, csrv);
  k_scatter<<<NCHUNK*NXCD, 256, 0, stream>>>(src, dst, cursor, csrv);
  k_wedge0 <<<(NN*CAP)/256, 256, 0, stream>>>(csrv, cursor, el0, er0, wt);
  k_agg0   <<<NN/4, 256, 0, stream>>>((const unsigned short*)z0b, wt, cursor, csrv, b0, (unsigned short*)hb);
  k_gemm1  <<<(NN+63)/64, 256, 0, stream>>>(hb, W1, al1, ar1, z1b, el1, er1);
  k_agg1   <<<NN/4, 256, 0, stream>>>((const unsigned short*)z1b, el1, er1, cursor, csrv, b1, out);
}

// Round 14
// 247.807 us; speedup vs baseline: 1.0490x; 1.0490x over previous
//
#include <hip/hip_runtime.h>
#include <stdint.h>

#define NN 50000
#define EE 800000
#define CAP 48        // slots/node; deg ~Poisson(16), max over 50K ~35 incl self-loop
#define NXCD 8
#define NPX 6250      // NN / NXCD
#define EPB 2048      // edges per scatter block
#define NCHUNK 391    // ceil(EE / EPB)

typedef __bf16 bf16x8 __attribute__((ext_vector_type(8)));
typedef float  f32x4  __attribute__((ext_vector_type(4)));

__device__ __forceinline__ float bflo(unsigned int w){ union{unsigned int i;float f;}c; c.i=w<<16; return c.f; }
__device__ __forceinline__ float bfhi(unsigned int w){ union{unsigned int i;float f;}c; c.i=w&0xFFFF0000u; return c.f; }
__device__ __forceinline__ float bfs(unsigned short u){ union{unsigned int i;float f;}c; c.i=((unsigned int)u)<<16; return c.f; }
__device__ __forceinline__ bf16x8 bf8_zero(){
  bf16x8 v;
  #pragma unroll
  for (int j=0;j<8;++j) v[j]=(__bf16)0.f;
  return v;
}

// ---------- prep: W0 [256,128] f32 -> bf16 MFMA-B fragment table Wg[32][128][8] ----------
__global__ __launch_bounds__(256) void k_prepW0(const float* __restrict__ W0,
                                                __bf16* __restrict__ Wg){
  int tg = blockIdx.x*256 + threadIdx.x;
  if (tg >= 4096) return;
  int k8 = tg >> 7, n = tg & 127;
  bf16x8 v;
  #pragma unroll
  for (int j=0;j<8;++j) v[j] = (__bf16)W0[(k8*8+j)*128 + n];
  *(bf16x8*)(Wg + ((size_t)(k8*128 + n))*8) = v;
}

// ---------- GEMM0 (MFMA bf16, LDS-free): z0b = x @ W0, + el0/er0 + self-loop CSR init ----------
__global__ __launch_bounds__(256) void k_gemm0(const float* __restrict__ x,
    const __bf16* __restrict__ Wg, const float* __restrict__ al0, const float* __restrict__ ar0,
    __bf16* __restrict__ z0b, float* __restrict__ el0, float* __restrict__ er0,
    int* __restrict__ cursor, int* __restrict__ csrv){
  const int tid = threadIdx.x;
  const int wv = tid >> 6, ln = tid & 63, q = ln >> 4, mr = ln & 15;
  const int nhalf = wv & 1, mhalf = wv >> 1;
  const int m0w = blockIdx.x*64 + mhalf*32;
  const int n0w = nhalf*64;
  f32x4 acc[2][4];
  #pragma unroll
  for (int mt=0;mt<2;++mt)
    #pragma unroll
    for (int nt=0;nt<4;++nt) acc[mt][nt] = (f32x4){0.f,0.f,0.f,0.f};
  const bool av0 = (m0w + mr) < NN;
  const bool av1 = (m0w + 16 + mr) < NN;
  const float* xr0 = x + (size_t)(m0w + mr)*256;
  const float* xr1 = x + (size_t)(m0w + 16 + mr)*256;
  #pragma unroll
  for (int kc=0;kc<8;++kc){
    int ko = kc*32 + q*8;
    bf16x8 a0 = bf8_zero(), a1 = bf8_zero();
    if (av0){
      float4 p = *(const float4*)(xr0 + ko);
      float4 p2 = *(const float4*)(xr0 + ko + 4);
      a0[0]=(__bf16)p.x; a0[1]=(__bf16)p.y; a0[2]=(__bf16)p.z; a0[3]=(__bf16)p.w;
      a0[4]=(__bf16)p2.x; a0[5]=(__bf16)p2.y; a0[6]=(__bf16)p2.z; a0[7]=(__bf16)p2.w;
    }
    if (av1){
      float4 p = *(const float4*)(xr1 + ko);
      float4 p2 = *(const float4*)(xr1 + ko + 4);
      a1[0]=(__bf16)p.x; a1[1]=(__bf16)p.y; a1[2]=(__bf16)p.z; a1[3]=(__bf16)p.w;
      a1[4]=(__bf16)p2.x; a1[5]=(__bf16)p2.y; a1[6]=(__bf16)p2.z; a1[7]=(__bf16)p2.w;
    }
    const __bf16* wb = Wg + ((size_t)((kc*4+q)*128 + n0w + mr))*8;
    #pragma unroll
    for (int nt=0;nt<4;++nt){
      bf16x8 bf = *(const bf16x8*)(wb + (size_t)nt*16*8);
      acc[0][nt] = __builtin_amdgcn_mfma_f32_16x16x32_bf16(a0, bf, acc[0][nt], 0,0,0);
      acc[1][nt] = __builtin_amdgcn_mfma_f32_16x16x32_bf16(a1, bf, acc[1][nt], 0,0,0);
    }
  }
  float alv[4], arv[4];
  #pragma unroll
  for (int nt=0;nt<4;++nt){ int c = n0w + nt*16 + mr; alv[nt]=al0[c]; arv[nt]=ar0[c]; }
  #pragma unroll
  for (int mt=0;mt<2;++mt){
    #pragma unroll
    for (int r=0;r<4;++r){
      int grow = m0w + mt*16 + q*4 + r;
      if (grow < NN){
        #pragma unroll
        for (int nt=0;nt<4;++nt)
          z0b[(size_t)grow*128 + n0w + nt*16 + mr] = (__bf16)acc[mt][nt][r];
      }
      float pl0 = acc[mt][0][r]*alv[0] + acc[mt][1][r]*alv[1];
      float pr0 = acc[mt][0][r]*arv[0] + acc[mt][1][r]*arv[1];
      float pl1 = acc[mt][2][r]*alv[2] + acc[mt][3][r]*alv[3];
      float pr1 = acc[mt][2][r]*arv[2] + acc[mt][3][r]*arv[3];
      #pragma unroll
      for (int off=1; off<16; off<<=1){
        pl0 += __shfl_xor(pl0, off, 16); pr0 += __shfl_xor(pr0, off, 16);
        pl1 += __shfl_xor(pl1, off, 16); pr1 += __shfl_xor(pr1, off, 16);
      }
      if (mr==0 && grow<NN){
        el0[grow*4 + 2*nhalf]   = pl0; er0[grow*4 + 2*nhalf]   = pr0;
        el0[grow*4 + 2*nhalf+1] = pl1; er0[grow*4 + 2*nhalf+1] = pr1;
        if (nhalf==0){ csrv[(size_t)grow*CAP] = grow; cursor[grow] = 1; }
      }
    }
  }
}

// ---------- scatter (XCD-partitioned, single pass) ----------
__global__ __launch_bounds__(256) void k_scatter(const int* __restrict__ src,
    const int* __restrict__ dst, int* __restrict__ cursor, int* __restrict__ csrv){
  const int xcd = blockIdx.x & 7;
  const int chunk = blockIdx.x >> 3;
  const int lo = xcd*NPX, hi = lo + NPX;
  int e = chunk*EPB + threadIdx.x;
  #pragma unroll
  for (int it=0; it<EPB/256; ++it, e += 256){
    if (e < EE){
      int d = dst[e];
      if (d >= lo && d < hi){
        int s = src[e];
        unsigned int inv = (s==d) ? 0x80000000u : 0u;
        int pos = atomicAdd(&cursor[d], 1);
        csrv[(size_t)d*CAP + pos] = (int)((unsigned int)s | inv);
      }
    }
  }
}

// ---------- wedge0: one thread per CSR slot -> 4-head bf16 softmax weights ----------
__global__ __launch_bounds__(256) void k_wedge0(const int* __restrict__ csrv,
    const int* __restrict__ cursor, const float* __restrict__ el0,
    const float* __restrict__ er0, unsigned short* __restrict__ wt){
  int slot = blockIdx.x*256 + threadIdx.x;
  int node = slot / CAP;
  int si = slot - node*CAP;
  if (si >= cursor[node]) return;
  int v = csrv[slot];
  int u = v & 0x7FFFFFFF;
  float4 ls = *(const float4*)(el0 + (size_t)u*4);
  float4 rd = *(const float4*)(er0 + (size_t)node*4);
  float e0=ls.x+rd.x; e0 = e0>0.f?e0:0.2f*e0;
  float e1=ls.y+rd.y; e1 = e1>0.f?e1:0.2f*e1;
  float e2=ls.z+rd.z; e2 = e2>0.f?e2:0.2f*e2;
  float e3=ls.w+rd.w; e3 = e3>0.f?e3:0.2f*e3;
  bool inv = (v < 0);
  union { __bf16 b[4]; uint2 u2; } pk;
  pk.b[0]=(__bf16)(inv?0.f:__expf(e0)); pk.b[1]=(__bf16)(inv?0.f:__expf(e1));
  pk.b[2]=(__bf16)(inv?0.f:__expf(e2)); pk.b[3]=(__bf16)(inv?0.f:__expf(e3));
  *(uint2*)(wt + (size_t)slot*4) = pk.u2;
}

// ---------- wedge1: one thread per CSR slot -> 1-head bf16 weight ----------
__global__ __launch_bounds__(256) void k_wedge1(const int* __restrict__ csrv,
    const int* __restrict__ cursor, const float* __restrict__ el1,
    const float* __restrict__ er1, unsigned short* __restrict__ wt1){
  int slot = blockIdx.x*256 + threadIdx.x;
  int node = slot / CAP;
  int si = slot - node*CAP;
  if (si >= cursor[node]) return;
  int v = csrv[slot];
  int u = v & 0x7FFFFFFF;
  float e = el1[u] + er1[node]; e = e>0.f?e:0.2f*e;
  float w = (v<0) ? 0.f : __expf(e);
  union { __bf16 b; unsigned short s; } pk; pk.b = (__bf16)w;
  wt1[slot] = pk.s;
}

// ---------- agg0: wave/node, 2 feats/lane; explicit 8-batch; weights precomputed ----------
__global__ __launch_bounds__(256) void k_agg0(const unsigned short* __restrict__ z0b,
    const unsigned short* __restrict__ wt,
    const int* __restrict__ cursor, const int* __restrict__ csrv,
    const float* __restrict__ b0, unsigned short* __restrict__ hb){
  int lane = threadIdx.x & 63;
  int i = __builtin_amdgcn_readfirstlane(blockIdx.x*4 + (threadIdx.x >> 6));
  int h1 = lane >> 4;
  int lane2 = lane << 1;
  float ax=0.f, ay=0.f, s=0.f;
  int p = i*CAP, pe = p + cursor[i];
  for (; p+8<=pe; p+=8){
    int4 va = *(const int4*)(csrv + p);
    int4 vb = *(const int4*)(csrv + p + 4);
    int v[8] = {va.x,va.y,va.z,va.w,vb.x,vb.y,vb.z,vb.w};
    float w[8];
    #pragma unroll
    for (int j=0;j<8;++j) w[j] = bfs(wt[(size_t)(p+j)*4 + h1]);
    unsigned int zw[8];
    #pragma unroll
    for (int j=0;j<8;++j)
      zw[j] = *(const unsigned int*)(z0b + (size_t)(v[j]&0x7FFFFFFF)*128 + lane2);
    #pragma unroll
    for (int j=0;j<8;++j){
      s += w[j]; ax = fmaf(w[j], bflo(zw[j]), ax); ay = fmaf(w[j], bfhi(zw[j]), ay);
    }
  }
  for (; p+4<=pe; p+=4){
    int4 va = *(const int4*)(csrv + p);
    int v[4] = {va.x,va.y,va.z,va.w};
    float w[4];
    #pragma unroll
    for (int j=0;j<4;++j) w[j] = bfs(wt[(size_t)(p+j)*4 + h1]);
    unsigned int zw[4];
    #pragma unroll
    for (int j=0;j<4;++j)
      zw[j] = *(const unsigned int*)(z0b + (size_t)(v[j]&0x7FFFFFFF)*128 + lane2);
    #pragma unroll
    for (int j=0;j<4;++j){
      s += w[j]; ax = fmaf(w[j], bflo(zw[j]), ax); ay = fmaf(w[j], bfhi(zw[j]), ay);
    }
  }
  for (; p<pe; ++p){
    int u = csrv[p] & 0x7FFFFFFF;
    float w = bfs(wt[(size_t)p*4 + h1]);
    unsigned int zw = *(const unsigned int*)(z0b + (size_t)u*128 + lane2);
    s += w; ax = fmaf(w, bflo(zw), ax); ay = fmaf(w, bfhi(zw), ay);
  }
  float inv = 1.f/s;
  float ox = ax*inv + b0[lane*2], oy = ay*inv + b0[lane*2+1];
  ox = ox>0.f?ox:__expf(ox)-1.f; oy = oy>0.f?oy:__expf(oy)-1.f;
  union { __bf16 b[2]; unsigned int u; } pk;
  pk.b[0]=(__bf16)ox; pk.b[1]=(__bf16)oy;
  *(unsigned int*)(hb + (size_t)i*128 + lane2) = pk.u;
}

// ---------- GEMM1 (MFMA bf16): z1b = h @ W1 [128x40], + fused el1/er1 ----------
__global__ __launch_bounds__(256) void k_gemm1(const __bf16* __restrict__ hb,
    const float* __restrict__ W1, const float* __restrict__ al1, const float* __restrict__ ar1,
    __bf16* __restrict__ z1b, float* __restrict__ el1, float* __restrict__ er1){
  __shared__ __bf16 Blds[16][48][8];
  const int tid = threadIdx.x;
  for (int t=tid; t<16*48*8; t+=256) (&Blds[0][0][0])[t] = (__bf16)0.f;
  __syncthreads();
  for (int t=tid; t<5120; t+=256){
    int k = t/40, n = t - k*40;
    Blds[k>>3][n][k&7] = (__bf16)W1[t];
  }
  __syncthreads();
  const int wm = tid >> 6, ln = tid & 63, q = ln >> 4, mr = ln & 15;
  const int m0 = blockIdx.x*64 + wm*16;
  const int arow = m0 + mr;
  const bool av = (arow < NN);
  f32x4 acc[3];
  #pragma unroll
  for (int nt=0;nt<3;++nt) acc[nt] = (f32x4){0.f,0.f,0.f,0.f};
  #pragma unroll
  for (int kc=0;kc<4;++kc){
    bf16x8 af = bf8_zero();
    if (av) af = *(const bf16x8*)(hb + (size_t)arow*128 + kc*32 + q*8);
    #pragma unroll
    for (int nt=0;nt<3;++nt){
      bf16x8 bf = *(const bf16x8*)&Blds[kc*4+q][nt*16+mr][0];
      acc[nt] = __builtin_amdgcn_mfma_f32_16x16x32_bf16(af, bf, acc[nt], 0,0,0);
    }
  }
  float alv[3], arv[3];
  #pragma unroll
  for (int nt=0;nt<3;++nt){
    int c = nt*16+mr;
    alv[nt] = (c<40) ? al1[c] : 0.f;
    arv[nt] = (c<40) ? ar1[c] : 0.f;
  }
  #pragma unroll
  for (int r=0;r<4;++r){
    int grow = m0 + q*4 + r;
    if (grow < NN){
      #pragma unroll
      for (int nt=0;nt<3;++nt){
        int c = nt*16+mr;
        if (c < 40) z1b[(size_t)grow*40 + c] = (__bf16)acc[nt][r];
      }
    }
    float pl = acc[0][r]*alv[0] + acc[1][r]*alv[1] + acc[2][r]*alv[2];
    float pr = acc[0][r]*arv[0] + acc[1][r]*arv[1] + acc[2][r]*arv[2];
    #pragma unroll
    for (int off=1; off<16; off<<=1){ pl += __shfl_xor(pl, off, 16); pr += __shfl_xor(pr, off, 16); }
    if (mr==0 && grow<NN){ el1[grow]=pl; er1[grow]=pr; }
  }
}

// ---------- agg1: wave/node, 2 feats/lane (lanes 0..19); explicit 8-batch; wt1 precomputed ----------
__global__ __launch_bounds__(256) void k_agg1(const unsigned short* __restrict__ z1b,
    const unsigned short* __restrict__ wt1,
    const int* __restrict__ cursor, const int* __restrict__ csrv,
    const float* __restrict__ b1, float* __restrict__ out){
  int lane = threadIdx.x & 63;
  int i = __builtin_amdgcn_readfirstlane(blockIdx.x*4 + (threadIdx.x >> 6));
  int fl = (lane < 20) ? (lane<<1) : 0;
  float ax=0.f, ay=0.f, s=0.f;
  int p = i*CAP, pe = p + cursor[i];
  for (; p+8<=pe; p+=8){
    int4 va = *(const int4*)(csrv + p);
    int4 vb = *(const int4*)(csrv + p + 4);
    int v[8] = {va.x,va.y,va.z,va.w,vb.x,vb.y,vb.z,vb.w};
    uint4 qw = *(const uint4*)(wt1 + p);            // 8 bf16 weights, wave-uniform
    float w[8] = {bflo(qw.x),bfhi(qw.x),bflo(qw.y),bfhi(qw.y),
                  bflo(qw.z),bfhi(qw.z),bflo(qw.w),bfhi(qw.w)};
    unsigned int zw[8];
    #pragma unroll
    for (int j=0;j<8;++j)
      zw[j] = *(const unsigned int*)(z1b + (size_t)(v[j]&0x7FFFFFFF)*40 + fl);
    #pragma unroll
    for (int j=0;j<8;++j){
      s += w[j]; ax = fmaf(w[j], bflo(zw[j]), ax); ay = fmaf(w[j], bfhi(zw[j]), ay);
    }
  }
  for (; p+4<=pe; p+=4){
    int4 va = *(const int4*)(csrv + p);
    int v[4] = {va.x,va.y,va.z,va.w};
    uint2 qw = *(const uint2*)(wt1 + p);
    float w[4] = {bflo(qw.x),bfhi(qw.x),bflo(qw.y),bfhi(qw.y)};
    unsigned int zw[4];
    #pragma unroll
    for (int j=0;j<4;++j)
      zw[j] = *(const unsigned int*)(z1b + (size_t)(v[j]&0x7FFFFFFF)*40 + fl);
    #pragma unroll
    for (int j=0;j<4;++j){
      s += w[j]; ax = fmaf(w[j], bflo(zw[j]), ax); ay = fmaf(w[j], bfhi(zw[j]), ay);
    }
  }
  for (; p<pe; ++p){
    int u = csrv[p] & 0x7FFFFFFF;
    float w = bfs(wt1[p]);
    unsigned int zw = *(const unsigned int*)(z1b + (size_t)u*40 + fl);
    s += w; ax = fmaf(w, bflo(zw), ax); ay = fmaf(w, bfhi(zw), ay);
  }
  if (lane < 20){
    float inv = 1.f/s;
    float ox = ax*inv + b1[lane*2], oy = ay*inv + b1[lane*2+1];
    ox = ox>0.f?ox:__expf(ox)-1.f; oy = oy>0.f?oy:__expf(oy)-1.f;
    *(float2*)(out + (size_t)i*40 + (lane<<1)) = make_float2(ox, oy);
  }
}

extern "C" void kernel_launch(void* const* d_in, const int* in_sizes, int n_in,
                              void* d_out, int out_size, void* d_ws, size_t ws_size,
                              hipStream_t stream){
  const float* x   = (const float*)d_in[0];
  const int*   src = (const int*)d_in[1];
  const int*   dst = (const int*)d_in[2];
  const float* W0  = (const float*)d_in[3];
  const float* al0 = (const float*)d_in[4];
  const float* ar0 = (const float*)d_in[5];
  const float* b0  = (const float*)d_in[6];
  const float* W1  = (const float*)d_in[7];
  const float* al1 = (const float*)d_in[8];
  const float* ar1 = (const float*)d_in[9];
  const float* b1  = (const float*)d_in[10];
  float* out = (float*)d_out;

  // ws layout (~60.7 MB); wt1 aliases hb (hb dead after gemm1)
  __bf16* z0b = (__bf16*)d_ws;                       // NN*128 bf16      12.8 MB
  __bf16* hb  = z0b + (size_t)NN*128;                // NN*128 bf16      12.8 MB
  __bf16* z1b = hb  + (size_t)NN*128;                // NN*40  bf16       4.0 MB
  __bf16* Wg  = z1b + (size_t)NN*40;                 // 32768 bf16       64 KB
  unsigned short* wt = (unsigned short*)(Wg + 32768);// NN*CAP*4 bf16    19.2 MB
  float* el0 = (float*)(wt + (size_t)NN*CAP*4);      // NN*4
  float* er0 = el0 + (size_t)NN*4;                   // NN*4
  float* el1 = er0 + (size_t)NN*4;                   // NN
  float* er1 = el1 + NN;                             // NN
  int* cursor = (int*)(er1 + NN);                    // NN
  int* csrv   = cursor + NN;                         // NN*CAP            9.6 MB
  unsigned short* wt1 = (unsigned short*)hb;         // NN*CAP bf16 (aliases hb)

  k_prepW0 <<<16, 256, 0, stream>>>(W0, Wg);
  k_gemm0<<<(NN+63)/64, 256, 0, stream>>>(x, Wg, al0, ar0, z0b, el0, er0, cursor, csrv);
  k_scatter<<<NCHUNK*NXCD, 256, 0, stream>>>(src, dst, cursor, csrv);
  k_wedge0<<<(NN*CAP)/256, 256, 0, stream>>>(csrv, cursor, el0, er0, wt);
  k_agg0 <<<NN/4, 256, 0, stream>>>((const unsigned short*)z0b, wt, cursor, csrv, b0, (unsigned short*)hb);
  k_gemm1<<<(NN+63)/64, 256, 0, stream>>>(hb, W1, al1, ar1, z1b, el1, er1);
  k_wedge1<<<(NN*CAP)/256, 256, 0, stream>>>(csrv, cursor, el1, er1, wt1);
  k_agg1 <<<NN/4, 256, 0, stream>>>((const unsigned short*)z1b, wt1, cursor, csrv, b1, out);
}